// Round 17
// baseline (444.866 us; speedup 1.0000x reference)
//
#include <hip/hip_runtime.h>
#include <stdint.h>

typedef unsigned short u16;
typedef __bf16 bf16x8 __attribute__((ext_vector_type(8)));
typedef float f32x4 __attribute__((ext_vector_type(4)));

#define GLD16(gp, lp) __builtin_amdgcn_global_load_lds( \
    (__attribute__((address_space(1))) void*)(uintptr_t)(gp), \
    (__attribute__((address_space(3))) void*)(uintptr_t)(lp), 16, 0, 0)

#define MM(a, b, c) __builtin_amdgcn_mfma_f32_16x16x32_bf16(a, b, c, 0, 0, 0)

__device__ __forceinline__ u16 f2bf(float f) {
  uint32_t u = __builtin_bit_cast(uint32_t, f);
  u += 0x7FFFu + ((u >> 16) & 1u);
  return (u16)(u >> 16);
}

// ---------------- fused weight transpose: 4 weights in one launch -------------------
__global__ __launch_bounds__(256) void wtrans4(const float* __restrict__ wq,
                                               const float* __restrict__ wo,
                                               const float* __restrict__ w1,
                                               const float* __restrict__ w2,
                                               u16* oq, u16* oo, u16* o1, u16* o2) {
  int b = blockIdx.x;
  const float* w; u16* wt; int K, Nn, bx, by;
  if (b < 768)       { w = wq; wt = oq; K = 1024; Nn = 3072; bx = b % 48; by = b / 48; }
  else if (b < 1024) { b -= 768;  w = wo; wt = oo; K = 1024; Nn = 1024; bx = b & 15; by = b >> 4; }
  else if (b < 2048) { b -= 1024; w = w1; wt = o1; K = 1024; Nn = 4096; bx = b & 63; by = b >> 6; }
  else               { b -= 2048; w = w2; wt = o2; K = 4096; Nn = 1024; bx = b & 15; by = b >> 4; }
  __shared__ float tile[64][68];
  const int c0 = bx << 6, r0 = by << 6;
  const int t = threadIdx.x, tr = t >> 2, tc = t & 3;
#pragma unroll
  for (int p = 0; p < 4; ++p) {
    float4 v = *(const float4*)&w[(size_t)(r0 + tr) * Nn + c0 + tc * 4 + p * 16];
    tile[tr][tc * 4 + p * 16 + 0] = v.x;
    tile[tr][tc * 4 + p * 16 + 1] = v.y;
    tile[tr][tc * 4 + p * 16 + 2] = v.z;
    tile[tr][tc * 4 + p * 16 + 3] = v.w;
  }
  __syncthreads();
#pragma unroll
  for (int p = 0; p < 4; ++p) {
    u16 e0 = f2bf(tile[tc * 4 + p * 16 + 0][tr]);
    u16 e1 = f2bf(tile[tc * 4 + p * 16 + 1][tr]);
    u16 e2 = f2bf(tile[tc * 4 + p * 16 + 2][tr]);
    u16 e3 = f2bf(tile[tc * 4 + p * 16 + 3][tr]);
    uint2 o;
    o.x = (uint32_t)e0 | ((uint32_t)e1 << 16);
    o.y = (uint32_t)e2 | ((uint32_t)e3 << 16);
    *(uint2*)&wt[(size_t)(c0 + tr) * K + r0 + tc * 4 + p * 16] = o;
  }
}

// ---------------- LayerNorm: x[M][1024] f32 -> out bf16 ----------------------------
__global__ __launch_bounds__(256) void lnorm(const float* x, const float* __restrict__ g,
                                             const float* __restrict__ bta,
                                             u16* __restrict__ out) {
  const int lane = threadIdx.x & 63, wid = threadIdx.x >> 6;
  const size_t token = (size_t)blockIdx.x * 4 + wid;
  const float* row = x + token * 1024;
  float v[16];
#pragma unroll
  for (int i = 0; i < 4; ++i) {
    float4 f = *(const float4*)&row[(lane + i * 64) * 4];
    v[i * 4 + 0] = f.x; v[i * 4 + 1] = f.y; v[i * 4 + 2] = f.z; v[i * 4 + 3] = f.w;
  }
  float s = 0.f, s2 = 0.f;
#pragma unroll
  for (int i = 0; i < 16; ++i) { s += v[i]; s2 += v[i] * v[i]; }
  for (int off = 1; off < 64; off <<= 1) {
    s += __shfl_xor(s, off);
    s2 += __shfl_xor(s2, off);
  }
  const float mu = s * (1.0f / 1024.0f);
  const float var = s2 * (1.0f / 1024.0f) - mu * mu;
  const float rstd = rsqrtf(var + 1e-6f);
  u16* orow = out + token * 1024;
#pragma unroll
  for (int i = 0; i < 4; ++i) {
    const int c = (lane + i * 64) * 4;
    float4 gv = *(const float4*)&g[c];
    float4 bv = *(const float4*)&bta[c];
    u16 e0 = f2bf((v[i * 4 + 0] - mu) * rstd * gv.x + bv.x);
    u16 e1 = f2bf((v[i * 4 + 1] - mu) * rstd * gv.y + bv.y);
    u16 e2 = f2bf((v[i * 4 + 2] - mu) * rstd * gv.z + bv.z);
    u16 e3 = f2bf((v[i * 4 + 3] - mu) * rstd * gv.w + bv.w);
    uint2 o;
    o.x = (uint32_t)e0 | ((uint32_t)e1 << 16);
    o.y = (uint32_t)e2 | ((uint32_t)e3 << 16);
    *(uint2*)&orow[c] = o;
  }
}

// ---------------- wide-wave-tile + deferred reg-staged GEMM -------------------------
// C[M][N] = A[M][K](bf16) * Bt[N][K](bf16)^T.
// R16's staging (global->reg at iter top, ds_write deferred after MFMA block; no
// DMA drain) x R12's geometry (block 256x128, 4 waves 2x2, wave-tile 128x64, BK=32).
// LDS traffic = 48 KB reads + 24 KB writes per 2.1 MFLOP = 0.0343 B/FLOP (vs
// 0.0458 at 64x64) -> LDS-BW ceiling (the R16-confirmed binder, ~85-100 B/cyc/CU)
// rises 1.33x. 2-slot dbuf, slot = A 16KB + B 8KB = 24 KB -> 48 KB LDS, 2 blk/CU.
// Swizzle (PMC-verified 0 conflicts, R5): row = 32 bf16 = 4 chunks of 16B,
// phys chunk = logical ^ ((row>>1)&3); DMA-free, source pre-swizzled via gsub.
// EPI 0: +bias (cols<qlimit scaled) -> bf16; 1: +bias tanh-GELU -> bf16;
// EPI 2: +bias +res -> f32
template <int EPI>
__global__ __launch_bounds__(256, 2) void g97(const u16* __restrict__ A,
                                              const u16* __restrict__ Bt,
                                              const float* __restrict__ bias,
                                              const float* res, void* Cout,
                                              int Ndim, int K, float qscale,
                                              int qlimit, int gn) {
  __shared__ __align__(16) u16 lds[2][12288];  // slot: A 16KB + B 8KB
  const int tid = threadIdx.x, lane = tid & 63, wid = tid >> 6;
  const int wm = wid & 1, wn = wid >> 1;

  const int wg = blockIdx.x;
  const int swz = (wg & 7) * ((int)gridDim.x >> 3) + (wg >> 3);
  const int mblk = swz / gn, nb = swz - mblk * gn;
  const int m0 = mblk << 8, n0 = nb << 7;

  // staging: per instr, thread t -> row t>>2 (64 rows), linear chunk t&3,
  // global sub-chunk = (t&3) ^ ((t>>3)&3)   [= chunk ^ swizzle(row), row=t>>2]
  const int srow = tid >> 2;
  const int gsub = (tid & 3) ^ ((tid >> 3) & 3);
  const u16* Ag = A + (size_t)(m0 + srow) * K + gsub * 8;
  const u16* Bg = Bt + (size_t)(n0 + srow) * K + gsub * 8;
  const size_t rstep = (size_t)64 * K;
  char* lb = (char*)&lds[0][0];

  // fragment reads: row r, phys chunk g ^ ((r>>1)&3); 16-row steps preserve swizzle
  const int rrow = lane & 15, g = lane >> 4;
  const int xg = (g ^ ((rrow >> 1) & 3)) * 16;
  const int aoff = (wm * 128 + rrow) * 64 + xg;            // + mf*1024
  const int boff = 16384 + (wn * 64 + rrow) * 64 + xg;     // + nf*1024

  const f32x4 fzero = {0.f, 0.f, 0.f, 0.f};
  f32x4 acc[8][4];
#pragma unroll
  for (int i = 0; i < 8; ++i)
#pragma unroll
    for (int j = 0; j < 4; ++j) acc[i][j] = fzero;

  uint4 av0, av1, av2, av3, bv0, bv1;  // staged K-tile in flight (24 VGPR)

#define LDAB(kt) do { \
    const u16* a_ = Ag + (size_t)(kt) * 32; \
    const u16* b_ = Bg + (size_t)(kt) * 32; \
    av0 = *(const uint4*)(a_); \
    av1 = *(const uint4*)(a_ + rstep); \
    av2 = *(const uint4*)(a_ + 2 * rstep); \
    av3 = *(const uint4*)(a_ + 3 * rstep); \
    bv0 = *(const uint4*)(b_); \
    bv1 = *(const uint4*)(b_ + rstep); \
  } while (0)

#define WRAB(s) do { \
    char* d_ = lb + (s) * 24576; \
    *(uint4*)(d_ + tid * 16) = av0; \
    *(uint4*)(d_ + 4096 + tid * 16) = av1; \
    *(uint4*)(d_ + 8192 + tid * 16) = av2; \
    *(uint4*)(d_ + 12288 + tid * 16) = av3; \
    *(uint4*)(d_ + 16384 + tid * 16) = bv0; \
    *(uint4*)(d_ + 20480 + tid * 16) = bv1; \
  } while (0)

  const int nk = K >> 5;
  LDAB(0);
  WRAB(0);
  __syncthreads();
  for (int kt = 0; kt < nk; ++kt) {
    const bool pf = (kt + 1 < nk);
    if (pf) LDAB(kt + 1);  // issue all 6 loads early; latency hidden under MFMAs
    const char* sb = lb + (kt & 1) * 24576;
    bf16x8 af[8], bfr[4];
#pragma unroll
    for (int nf = 0; nf < 4; ++nf)
      bfr[nf] = *(const bf16x8*)(sb + boff + nf * 1024);
#pragma unroll
    for (int mf = 0; mf < 8; ++mf)
      af[mf] = *(const bf16x8*)(sb + aoff + mf * 1024);
#pragma unroll
    for (int mf = 0; mf < 8; ++mf)
#pragma unroll
      for (int nf = 0; nf < 4; ++nf)
        acc[mf][nf] = MM(af[mf], bfr[nf], acc[mf][nf]);
    if (pf) WRAB((kt + 1) & 1);  // deferred: loads had the full MFMA block to land
    __syncthreads();
  }
#undef LDAB
#undef WRAB

  const int g4 = g << 2;
#pragma unroll
  for (int nf = 0; nf < 4; ++nf) {
    const int col = n0 + wn * 64 + nf * 16 + rrow;
    const float bvb = bias[col];
    const float csf = (EPI == 0 && col < qlimit) ? qscale : 1.0f;
#pragma unroll
    for (int mf = 0; mf < 8; ++mf) {
#pragma unroll
      for (int r = 0; r < 4; ++r) {
        const int row = m0 + wm * 128 + mf * 16 + g4 + r;
        float v = acc[mf][nf][r] + bvb;
        if (EPI == 0) v *= csf;
        if (EPI == 1) {
          float sg = 1.0f / (1.0f + exp2f(-2.302264866f * (v + 0.044715f * v * v * v)));
          v *= sg;
        }
        if (EPI == 2) {
          v += res[(size_t)row * Ndim + col];
          ((float*)Cout)[(size_t)row * Ndim + col] = v;
        } else {
          ((u16*)Cout)[(size_t)row * Ndim + col] = f2bf(v);
        }
      }
    }
  }
}

// ---------------- V transpose: qkv V block -> vt[bh][d][n] bf16 --------------------
__global__ __launch_bounds__(256) void vtrans(const u16* __restrict__ qkv,
                                              u16* __restrict__ vt) {
  const int bh = blockIdx.y, b = bh >> 4, h = bh & 15;
  const int n0 = blockIdx.x << 6;
  __shared__ __align__(16) u16 tile[64][72];
  const int t = threadIdx.x, r = t >> 2, c = t & 3;
  const u16* src = qkv + (size_t)((b << 10) + n0 + r) * 3072 + 2048 + (h << 6);
#pragma unroll
  for (int p = 0; p < 2; ++p)
    *(uint4*)&tile[r][(c * 2 + p) * 8] = *(const uint4*)(src + (c * 2 + p) * 8);
  __syncthreads();
  u16* dst = vt + (size_t)((bh << 6) + r) * 1024 + n0;
#pragma unroll
  for (int p = 0; p < 2; ++p) {
    u16 o[8];
#pragma unroll
    for (int j = 0; j < 8; ++j) o[j] = tile[(c * 2 + p) * 8 + j][r];
    uint4 w;
    w.x = (uint32_t)o[0] | ((uint32_t)o[1] << 16);
    w.y = (uint32_t)o[2] | ((uint32_t)o[3] << 16);
    w.z = (uint32_t)o[4] | ((uint32_t)o[5] << 16);
    w.w = (uint32_t)o[6] | ((uint32_t)o[7] << 16);
    *(uint4*)&dst[(c * 2 + p) * 8] = w;
  }
}

// ---------------- flash attention (no-max softmax, swapped QK^T, K/V dbuf) ---------
__global__ __launch_bounds__(256) void attn64(const u16* __restrict__ qkv,
                                              const u16* __restrict__ vt,
                                              u16* __restrict__ aout) {
  const int bh = blockIdx.y, b = bh >> 4, h = bh & 15;
  const int q0 = blockIdx.x << 6;
  const int tid = threadIdx.x, lane = tid & 63, wid = tid >> 6;
  __shared__ __align__(16) u16 kl[2][4096];
  __shared__ __align__(16) u16 vl[2][4096];
  __shared__ __align__(16) u16 pl[4][1152];  // [wave][16 q][72]: P rows, k-major

  const int rrow = lane & 15;
  const int g = lane >> 4;
  const u16* qrow = qkv + (size_t)((b << 10) + q0 + (wid << 4) + rrow) * 3072 + (h << 6);
  bf16x8 qf0 = *(const bf16x8*)(qrow + (g << 3));
  bf16x8 qf1 = *(const bf16x8*)(qrow + 32 + (g << 3));

  const int sr = lane >> 3;
  const int lc = (lane & 7) ^ sr;
  const u16* kbase = qkv + (size_t)(b << 10) * 3072 + 1024 + (h << 6) +
                     (size_t)(16 * wid + sr) * 3072 + lc * 8;
  const u16* vbase = vt + (size_t)(bh << 6) * 1024 + (size_t)(16 * wid + sr) * 1024 + lc * 8;

  const f32x4 fzero = {0.f, 0.f, 0.f, 0.f};
  f32x4 oacc[4];
#pragma unroll
  for (int i = 0; i < 4; ++i) oacc[i] = fzero;
  f32x4 lacc = fzero;
  const int rcb = lane & 7;
  u16* plw = &pl[wid][0];

#define ASTAGE(t, s) do { \
    const int kt0_ = (t) << 6; \
    GLD16(kbase + (size_t)kt0_ * 3072, &kl[s][(2 * wid + 0) * 512]); \
    GLD16(kbase + (size_t)kt0_ * 3072 + 8 * 3072, &kl[s][(2 * wid + 1) * 512]); \
    GLD16(vbase + kt0_, &vl[s][(2 * wid + 0) * 512]); \
    GLD16(vbase + kt0_ + 8 * 1024, &vl[s][(2 * wid + 1) * 512]); \
  } while (0)

  ASTAGE(0, 0);
  __syncthreads();
  for (int t = 0; t < 16; ++t) {
    if (t + 1 < 16) ASTAGE(t + 1, (t + 1) & 1);
    const char* klp = (const char*)&kl[t & 1][0];
    const char* vlp = (const char*)&vl[t & 1][0];

    f32x4 s4[4];
#pragma unroll
    for (int i = 0; i < 4; ++i) s4[i] = fzero;
    __builtin_amdgcn_s_setprio(1);
#pragma unroll
    for (int nf = 0; nf < 4; ++nf) {
      bf16x8 k0 = *(const bf16x8*)(klp + (nf * 16 + rrow) * 128 + ((g + 0) ^ rcb) * 16);
      bf16x8 k1 = *(const bf16x8*)(klp + (nf * 16 + rrow) * 128 + ((g + 4) ^ rcb) * 16);
      s4[nf] = __builtin_amdgcn_mfma_f32_16x16x32_bf16(k0, qf0, s4[nf], 0, 0, 0);
      s4[nf] = __builtin_amdgcn_mfma_f32_16x16x32_bf16(k1, qf1, s4[nf], 0, 0, 0);
    }
    __builtin_amdgcn_s_setprio(0);

#pragma unroll
    for (int nf = 0; nf < 4; ++nf) {
      float p0 = exp2f(s4[nf][0]);
      float p1 = exp2f(s4[nf][1]);
      float p2 = exp2f(s4[nf][2]);
      float p3 = exp2f(s4[nf][3]);
      f32x4 pv = {p0, p1, p2, p3};
      lacc += pv;
      uint32_t a0 = __builtin_bit_cast(uint32_t, p0) + 0x8000u;
      uint32_t a1 = __builtin_bit_cast(uint32_t, p1) + 0x8000u;
      uint32_t a2 = __builtin_bit_cast(uint32_t, p2) + 0x8000u;
      uint32_t a3 = __builtin_bit_cast(uint32_t, p3) + 0x8000u;
      uint2 w;
      w.x = __builtin_amdgcn_perm(a1, a0, 0x07060302);
      w.y = __builtin_amdgcn_perm(a3, a2, 0x07060302);
      *(uint2*)(plw + rrow * 72 + nf * 16 + (g << 2)) = w;
    }

    bf16x8 pf0 = *(const bf16x8*)((const char*)plw + rrow * 144 + (g << 4));
    bf16x8 pf1 = *(const bf16x8*)((const char*)plw + rrow * 144 + (g << 4) + 64);
    __builtin_amdgcn_s_setprio(1);
#pragma unroll
    for (int nf = 0; nf < 4; ++nf) {
      bf16x8 v0 = *(const bf16x8*)(vlp + (nf * 16 + rrow) * 128 + ((g + 0) ^ rcb) * 16);
      bf16x8 v1 = *(const bf16x8*)(vlp + (nf * 16 + rrow) * 128 + ((g + 4) ^ rcb) * 16);
      oacc[nf] = __builtin_amdgcn_mfma_f32_16x16x32_bf16(pf0, v0, oacc[nf], 0, 0, 0);
      oacc[nf] = __builtin_amdgcn_mfma_f32_16x16x32_bf16(pf1, v1, oacc[nf], 0, 0, 0);
    }
    __builtin_amdgcn_s_setprio(0);
    __syncthreads();
  }
#undef ASTAGE

  float lsum = lacc[0] + lacc[1] + lacc[2] + lacc[3];
  lsum += __shfl_xor(lsum, 16);
  lsum += __shfl_xor(lsum, 32);
  const float inv = 1.0f / lsum;
  float invq[4];
#pragma unroll
  for (int r = 0; r < 4; ++r) {
    int bi = __builtin_amdgcn_ds_bpermute(((g << 2) + r) << 2,
                                          __builtin_bit_cast(int, inv));
    invq[r] = __builtin_bit_cast(float, bi);
  }
  u16* ob = aout + (size_t)((b << 10) + q0 + (wid << 4)) * 1024 + (h << 6);
#pragma unroll
  for (int nf = 0; nf < 4; ++nf)
#pragma unroll
    for (int r = 0; r < 4; ++r)
      ob[(size_t)(g * 4 + r) * 1024 + nf * 16 + rrow] = f2bf(oacc[nf][r] * invq[r]);
}

// ---------------- launcher ---------------------------------------------------------
extern "C" void kernel_launch(void* const* d_in, const int* in_sizes, int n_in,
                              void* d_out, int out_size, void* d_ws, size_t ws_size,
                              hipStream_t stream) {
  const float* x = (const float*)d_in[0];
  const float* ln1_g = (const float*)d_in[1];
  const float* ln1_b = (const float*)d_in[2];
  const float* w_qkv = (const float*)d_in[3];
  const float* b_qkv = (const float*)d_in[4];
  const float* w_o = (const float*)d_in[5];
  const float* b_o = (const float*)d_in[6];
  const float* ln2_g = (const float*)d_in[7];
  const float* ln2_b = (const float*)d_in[8];
  const float* w_fc1 = (const float*)d_in[9];
  const float* b_fc1 = (const float*)d_in[10];
  const float* w_fc2 = (const float*)d_in[11];
  const float* b_fc2 = (const float*)d_in[12];
  float* out = (float*)d_out;

  char* w = (char*)d_ws;
  u16* wqkvT = (u16*)w; w += (size_t)3072 * 1024 * 2;
  u16* woT   = (u16*)w; w += (size_t)1024 * 1024 * 2;
  u16* wfc1T = (u16*)w; w += (size_t)4096 * 1024 * 2;
  u16* wfc2T = (u16*)w; w += (size_t)1024 * 4096 * 2;
  u16* xn    = (u16*)w; w += (size_t)8192 * 1024 * 2;
  u16* qkvb  = (u16*)w; w += (size_t)8192 * 3072 * 2;
  u16* vtb   = (u16*)w; w += (size_t)128 * 64 * 1024 * 2;
  u16* attnb = (u16*)w; w += (size_t)8192 * 1024 * 2;
  u16* hbuf  = qkvb;  // overlay: qkv+vt dead when h is produced

  const float QS = 0.18033688011112042f;  // 0.125 * log2(e)

  wtrans4<<<3072, 256, 0, stream>>>(w_qkv, w_o, w_fc1, w_fc2, wqkvT, woT, wfc1T, wfc2T);

  lnorm<<<2048, 256, 0, stream>>>(x, ln1_g, ln1_b, xn);
  g97<0><<<768, 256, 0, stream>>>(xn, wqkvT, b_qkv, nullptr, qkvb, 3072, 1024, QS, 1024, 24);
  vtrans<<<dim3(16, 128), 256, 0, stream>>>(qkvb, vtb);
  attn64<<<dim3(16, 128), 256, 0, stream>>>(qkvb, vtb, attnb);
  g97<2><<<256, 256, 0, stream>>>(attnb, woT, b_o, x, out, 1024, 1024, 1.f, 0, 8);
  lnorm<<<2048, 256, 0, stream>>>(out, ln2_g, ln2_b, xn);
  g97<1><<<1024, 256, 0, stream>>>(xn, wfc1T, b_fc1, nullptr, hbuf, 4096, 1024, 1.f, 0, 32);
  g97<2><<<256, 256, 0, stream>>>(hbuf, wfc2T, b_fc2, out, out, 1024, 4096, 1.f, 0, 8);
}

// Round 18
// 400.951 us; speedup vs baseline: 1.1095x; 1.1095x over previous
//
#include <hip/hip_runtime.h>
#include <stdint.h>

typedef unsigned short u16;
typedef __bf16 bf16x8 __attribute__((ext_vector_type(8)));
typedef float f32x4 __attribute__((ext_vector_type(4)));

#define GLD16(gp, lp) __builtin_amdgcn_global_load_lds( \
    (__attribute__((address_space(1))) void*)(uintptr_t)(gp), \
    (__attribute__((address_space(3))) void*)(uintptr_t)(lp), 16, 0, 0)

#define MM(a, b, c) __builtin_amdgcn_mfma_f32_16x16x32_bf16(a, b, c, 0, 0, 0)

__device__ __forceinline__ u16 f2bf(float f) {
  uint32_t u = __builtin_bit_cast(uint32_t, f);
  u += 0x7FFFu + ((u >> 16) & 1u);
  return (u16)(u >> 16);
}

// ---------------- fused weight transpose: 4 weights in one launch -------------------
__global__ __launch_bounds__(256) void wtrans4(const float* __restrict__ wq,
                                               const float* __restrict__ wo,
                                               const float* __restrict__ w1,
                                               const float* __restrict__ w2,
                                               u16* oq, u16* oo, u16* o1, u16* o2) {
  int b = blockIdx.x;
  const float* w; u16* wt; int K, Nn, bx, by;
  if (b < 768)       { w = wq; wt = oq; K = 1024; Nn = 3072; bx = b % 48; by = b / 48; }
  else if (b < 1024) { b -= 768;  w = wo; wt = oo; K = 1024; Nn = 1024; bx = b & 15; by = b >> 4; }
  else if (b < 2048) { b -= 1024; w = w1; wt = o1; K = 1024; Nn = 4096; bx = b & 63; by = b >> 6; }
  else               { b -= 2048; w = w2; wt = o2; K = 4096; Nn = 1024; bx = b & 15; by = b >> 4; }
  __shared__ float tile[64][68];
  const int c0 = bx << 6, r0 = by << 6;
  const int t = threadIdx.x, tr = t >> 2, tc = t & 3;
#pragma unroll
  for (int p = 0; p < 4; ++p) {
    float4 v = *(const float4*)&w[(size_t)(r0 + tr) * Nn + c0 + tc * 4 + p * 16];
    tile[tr][tc * 4 + p * 16 + 0] = v.x;
    tile[tr][tc * 4 + p * 16 + 1] = v.y;
    tile[tr][tc * 4 + p * 16 + 2] = v.z;
    tile[tr][tc * 4 + p * 16 + 3] = v.w;
  }
  __syncthreads();
#pragma unroll
  for (int p = 0; p < 4; ++p) {
    u16 e0 = f2bf(tile[tc * 4 + p * 16 + 0][tr]);
    u16 e1 = f2bf(tile[tc * 4 + p * 16 + 1][tr]);
    u16 e2 = f2bf(tile[tc * 4 + p * 16 + 2][tr]);
    u16 e3 = f2bf(tile[tc * 4 + p * 16 + 3][tr]);
    uint2 o;
    o.x = (uint32_t)e0 | ((uint32_t)e1 << 16);
    o.y = (uint32_t)e2 | ((uint32_t)e3 << 16);
    *(uint2*)&wt[(size_t)(c0 + tr) * K + r0 + tc * 4 + p * 16] = o;
  }
}

// ---------------- LayerNorm: x[M][1024] f32 -> out bf16 ----------------------------
__global__ __launch_bounds__(256) void lnorm(const float* x, const float* __restrict__ g,
                                             const float* __restrict__ bta,
                                             u16* __restrict__ out) {
  const int lane = threadIdx.x & 63, wid = threadIdx.x >> 6;
  const size_t token = (size_t)blockIdx.x * 4 + wid;
  const float* row = x + token * 1024;
  float v[16];
#pragma unroll
  for (int i = 0; i < 4; ++i) {
    float4 f = *(const float4*)&row[(lane + i * 64) * 4];
    v[i * 4 + 0] = f.x; v[i * 4 + 1] = f.y; v[i * 4 + 2] = f.z; v[i * 4 + 3] = f.w;
  }
  float s = 0.f, s2 = 0.f;
#pragma unroll
  for (int i = 0; i < 16; ++i) { s += v[i]; s2 += v[i] * v[i]; }
  for (int off = 1; off < 64; off <<= 1) {
    s += __shfl_xor(s, off);
    s2 += __shfl_xor(s2, off);
  }
  const float mu = s * (1.0f / 1024.0f);
  const float var = s2 * (1.0f / 1024.0f) - mu * mu;
  const float rstd = rsqrtf(var + 1e-6f);
  u16* orow = out + token * 1024;
#pragma unroll
  for (int i = 0; i < 4; ++i) {
    const int c = (lane + i * 64) * 4;
    float4 gv = *(const float4*)&g[c];
    float4 bv = *(const float4*)&bta[c];
    u16 e0 = f2bf((v[i * 4 + 0] - mu) * rstd * gv.x + bv.x);
    u16 e1 = f2bf((v[i * 4 + 1] - mu) * rstd * gv.y + bv.y);
    u16 e2 = f2bf((v[i * 4 + 2] - mu) * rstd * gv.z + bv.z);
    u16 e3 = f2bf((v[i * 4 + 3] - mu) * rstd * gv.w + bv.w);
    uint2 o;
    o.x = (uint32_t)e0 | ((uint32_t)e1 << 16);
    o.y = (uint32_t)e2 | ((uint32_t)e3 << 16);
    *(uint2*)&orow[c] = o;
  }
}

// ---------------- split-staged GEMM (R15 best-known-good) ---------------------------
// C = A[M][K](bf16) * Bt[N][K](bf16)^T. 128x128, 4 waves 2x2, BK=64, 2-slot dbuf
// (64 KB LDS), 2 blocks/CU. B via global_load_lds DMA; A via global->reg (issued
// at iter top) -> ds_write deferred after the MFMA block. Swizzle (PMC-0):
// phys 16B-chunk = logical ^ (row&7); 2nd k32-half read base = base ^ 64.
// Measured: 105 us on FC1 (~654 TF) = top of the documented 2-phase band.
// EPI 0: +bias (cols<qlimit scaled) -> bf16; 1: +bias tanh-GELU -> bf16;
// EPI 2: +bias +res -> f32
template <int EPI>
__global__ __launch_bounds__(256, 2) void g97(const u16* __restrict__ A,
                                              const u16* __restrict__ Bt,
                                              const float* __restrict__ bias,
                                              const float* res, void* Cout,
                                              int Ndim, int K, float qscale,
                                              int qlimit, int gn) {
  __shared__ __align__(16) u16 lds[2][16384];  // slot: A 16KB + B 16KB
  const int tid = threadIdx.x, lane = tid & 63, wid = tid >> 6;
  const int wm = wid & 1, wn = wid >> 1;

  const int wg = blockIdx.x;
  const int swz = (wg & 7) * ((int)gridDim.x >> 3) + (wg >> 3);
  const int mblk = swz / gn, nb = swz - mblk * gn;
  const int m0 = mblk << 7, n0 = nb << 7;

  const int srow = tid >> 3;
  const int schunk = (tid & 7) ^ (srow & 7);
  const u16* Ag = A + (size_t)(m0 + srow) * K + schunk * 8;
  const u16* Bg = Bt + (size_t)(n0 + srow) * K + schunk * 8;
  const size_t rstep = (size_t)32 * K;
  char* lb = (char*)&lds[0][0];

  const int rrow = lane & 15, g = lane >> 4;
  const int ph0 = (g ^ (rrow & 7)) * 16;
  const int aoff0 = (wm * 64 + rrow) * 128 + ph0;            // + mf*2048
  const int aoff1 = (wm * 64 + rrow) * 128 + (ph0 ^ 64);
  const int boff0 = 16384 + (wn * 64 + rrow) * 128 + ph0;    // + nf*2048
  const int boff1 = 16384 + (wn * 64 + rrow) * 128 + (ph0 ^ 64);

  const f32x4 fzero = {0.f, 0.f, 0.f, 0.f};
  f32x4 acc[4][4];
#pragma unroll
  for (int i = 0; i < 4; ++i)
#pragma unroll
    for (int j = 0; j < 4; ++j) acc[i][j] = fzero;

  uint4 av0, av1, av2, av3;  // A tile in flight (reg path)

#define LDA4(kt) do { \
    const u16* a_ = Ag + (size_t)(kt) * 64; \
    av0 = *(const uint4*)(a_); \
    av1 = *(const uint4*)(a_ + rstep); \
    av2 = *(const uint4*)(a_ + 2 * rstep); \
    av3 = *(const uint4*)(a_ + 3 * rstep); \
  } while (0)

#define WRA4(s) do { \
    char* d_ = lb + (s) * 32768; \
    *(uint4*)(d_ + tid * 16) = av0; \
    *(uint4*)(d_ + 4096 + tid * 16) = av1; \
    *(uint4*)(d_ + 8192 + tid * 16) = av2; \
    *(uint4*)(d_ + 12288 + tid * 16) = av3; \
  } while (0)

#define STGB4(kt, s) do { \
    char* d_ = lb + (s) * 32768; \
    const u16* b_ = Bg + (size_t)(kt) * 64; \
    GLD16(b_,             d_ + 16384 + tid * 16); \
    GLD16(b_ + rstep,     d_ + 20480 + tid * 16); \
    GLD16(b_ + 2 * rstep, d_ + 24576 + tid * 16); \
    GLD16(b_ + 3 * rstep, d_ + 28672 + tid * 16); \
  } while (0)

  const int nk = K >> 6;
  LDA4(0);
  WRA4(0);
  STGB4(0, 0);
  __syncthreads();
  for (int kt = 0; kt < nk; ++kt) {
    const bool pf = (kt + 1 < nk);
    if (pf) {
      LDA4(kt + 1);           // issue A loads early (latency hidden under MFMA)
      STGB4(kt + 1, (kt + 1) & 1);
    }
    const char* sb = lb + (kt & 1) * 32768;
    // ---- k-chunk 0
    bf16x8 af[4], bfr[4];
#pragma unroll
    for (int mf = 0; mf < 4; ++mf)
      af[mf] = *(const bf16x8*)(sb + aoff0 + mf * 2048);
#pragma unroll
    for (int nf = 0; nf < 4; ++nf)
      bfr[nf] = *(const bf16x8*)(sb + boff0 + nf * 2048);
#pragma unroll
    for (int mf = 0; mf < 4; ++mf)
#pragma unroll
      for (int nf = 0; nf < 4; ++nf)
        acc[mf][nf] = MM(af[mf], bfr[nf], acc[mf][nf]);
    // ---- k-chunk 1
#pragma unroll
    for (int mf = 0; mf < 4; ++mf)
      af[mf] = *(const bf16x8*)(sb + aoff1 + mf * 2048);
#pragma unroll
    for (int nf = 0; nf < 4; ++nf)
      bfr[nf] = *(const bf16x8*)(sb + boff1 + nf * 2048);
#pragma unroll
    for (int mf = 0; mf < 4; ++mf)
#pragma unroll
      for (int nf = 0; nf < 4; ++nf)
        acc[mf][nf] = MM(af[mf], bfr[nf], acc[mf][nf]);
    if (pf) WRA4((kt + 1) & 1);  // vmcnt waits only for av* (B DMA stays in flight)
    __syncthreads();
  }
#undef LDA4
#undef WRA4
#undef STGB4

  const int g4 = (lane >> 4) << 2;
#pragma unroll
  for (int nf = 0; nf < 4; ++nf) {
    const int col = n0 + wn * 64 + nf * 16 + rrow;
    const float bvb = bias[col];
    const float csf = (EPI == 0 && col < qlimit) ? qscale : 1.0f;
#pragma unroll
    for (int mf = 0; mf < 4; ++mf) {
#pragma unroll
      for (int r = 0; r < 4; ++r) {
        const int row = m0 + wm * 64 + mf * 16 + g4 + r;
        float v = acc[mf][nf][r] + bvb;
        if (EPI == 0) v *= csf;
        if (EPI == 1) {
          float sg = 1.0f / (1.0f + exp2f(-2.302264866f * (v + 0.044715f * v * v * v)));
          v *= sg;
        }
        if (EPI == 2) {
          v += res[(size_t)row * Ndim + col];
          ((float*)Cout)[(size_t)row * Ndim + col] = v;
        } else {
          ((u16*)Cout)[(size_t)row * Ndim + col] = f2bf(v);
        }
      }
    }
  }
}

// ---------------- V transpose: qkv V block -> vt[bh][d][n] bf16 --------------------
__global__ __launch_bounds__(256) void vtrans(const u16* __restrict__ qkv,
                                              u16* __restrict__ vt) {
  const int bh = blockIdx.y, b = bh >> 4, h = bh & 15;
  const int n0 = blockIdx.x << 6;
  __shared__ __align__(16) u16 tile[64][72];
  const int t = threadIdx.x, r = t >> 2, c = t & 3;
  const u16* src = qkv + (size_t)((b << 10) + n0 + r) * 3072 + 2048 + (h << 6);
#pragma unroll
  for (int p = 0; p < 2; ++p)
    *(uint4*)&tile[r][(c * 2 + p) * 8] = *(const uint4*)(src + (c * 2 + p) * 8);
  __syncthreads();
  u16* dst = vt + (size_t)((bh << 6) + r) * 1024 + n0;
#pragma unroll
  for (int p = 0; p < 2; ++p) {
    u16 o[8];
#pragma unroll
    for (int j = 0; j < 8; ++j) o[j] = tile[(c * 2 + p) * 8 + j][r];
    uint4 w;
    w.x = (uint32_t)o[0] | ((uint32_t)o[1] << 16);
    w.y = (uint32_t)o[2] | ((uint32_t)o[3] << 16);
    w.z = (uint32_t)o[4] | ((uint32_t)o[5] << 16);
    w.w = (uint32_t)o[6] | ((uint32_t)o[7] << 16);
    *(uint4*)&dst[(c * 2 + p) * 8] = w;
  }
}

// ---------------- flash attention (no-max softmax, swapped QK^T, K/V dbuf) ---------
__global__ __launch_bounds__(256) void attn64(const u16* __restrict__ qkv,
                                              const u16* __restrict__ vt,
                                              u16* __restrict__ aout) {
  const int bh = blockIdx.y, b = bh >> 4, h = bh & 15;
  const int q0 = blockIdx.x << 6;
  const int tid = threadIdx.x, lane = tid & 63, wid = tid >> 6;
  __shared__ __align__(16) u16 kl[2][4096];
  __shared__ __align__(16) u16 vl[2][4096];
  __shared__ __align__(16) u16 pl[4][1152];  // [wave][16 q][72]: P rows, k-major

  const int rrow = lane & 15;
  const int g = lane >> 4;
  const u16* qrow = qkv + (size_t)((b << 10) + q0 + (wid << 4) + rrow) * 3072 + (h << 6);
  bf16x8 qf0 = *(const bf16x8*)(qrow + (g << 3));
  bf16x8 qf1 = *(const bf16x8*)(qrow + 32 + (g << 3));

  const int sr = lane >> 3;
  const int lc = (lane & 7) ^ sr;
  const u16* kbase = qkv + (size_t)(b << 10) * 3072 + 1024 + (h << 6) +
                     (size_t)(16 * wid + sr) * 3072 + lc * 8;
  const u16* vbase = vt + (size_t)(bh << 6) * 1024 + (size_t)(16 * wid + sr) * 1024 + lc * 8;

  const f32x4 fzero = {0.f, 0.f, 0.f, 0.f};
  f32x4 oacc[4];
#pragma unroll
  for (int i = 0; i < 4; ++i) oacc[i] = fzero;
  f32x4 lacc = fzero;
  const int rcb = lane & 7;
  u16* plw = &pl[wid][0];

#define ASTAGE(t, s) do { \
    const int kt0_ = (t) << 6; \
    GLD16(kbase + (size_t)kt0_ * 3072, &kl[s][(2 * wid + 0) * 512]); \
    GLD16(kbase + (size_t)kt0_ * 3072 + 8 * 3072, &kl[s][(2 * wid + 1) * 512]); \
    GLD16(vbase + kt0_, &vl[s][(2 * wid + 0) * 512]); \
    GLD16(vbase + kt0_ + 8 * 1024, &vl[s][(2 * wid + 1) * 512]); \
  } while (0)

  ASTAGE(0, 0);
  __syncthreads();
  for (int t = 0; t < 16; ++t) {
    if (t + 1 < 16) ASTAGE(t + 1, (t + 1) & 1);
    const char* klp = (const char*)&kl[t & 1][0];
    const char* vlp = (const char*)&vl[t & 1][0];

    f32x4 s4[4];
#pragma unroll
    for (int i = 0; i < 4; ++i) s4[i] = fzero;
    __builtin_amdgcn_s_setprio(1);
#pragma unroll
    for (int nf = 0; nf < 4; ++nf) {
      bf16x8 k0 = *(const bf16x8*)(klp + (nf * 16 + rrow) * 128 + ((g + 0) ^ rcb) * 16);
      bf16x8 k1 = *(const bf16x8*)(klp + (nf * 16 + rrow) * 128 + ((g + 4) ^ rcb) * 16);
      s4[nf] = __builtin_amdgcn_mfma_f32_16x16x32_bf16(k0, qf0, s4[nf], 0, 0, 0);
      s4[nf] = __builtin_amdgcn_mfma_f32_16x16x32_bf16(k1, qf1, s4[nf], 0, 0, 0);
    }
    __builtin_amdgcn_s_setprio(0);

#pragma unroll
    for (int nf = 0; nf < 4; ++nf) {
      float p0 = exp2f(s4[nf][0]);
      float p1 = exp2f(s4[nf][1]);
      float p2 = exp2f(s4[nf][2]);
      float p3 = exp2f(s4[nf][3]);
      f32x4 pv = {p0, p1, p2, p3};
      lacc += pv;
      uint32_t a0 = __builtin_bit_cast(uint32_t, p0) + 0x8000u;
      uint32_t a1 = __builtin_bit_cast(uint32_t, p1) + 0x8000u;
      uint32_t a2 = __builtin_bit_cast(uint32_t, p2) + 0x8000u;
      uint32_t a3 = __builtin_bit_cast(uint32_t, p3) + 0x8000u;
      uint2 w;
      w.x = __builtin_amdgcn_perm(a1, a0, 0x07060302);
      w.y = __builtin_amdgcn_perm(a3, a2, 0x07060302);
      *(uint2*)(plw + rrow * 72 + nf * 16 + (g << 2)) = w;
    }

    bf16x8 pf0 = *(const bf16x8*)((const char*)plw + rrow * 144 + (g << 4));
    bf16x8 pf1 = *(const bf16x8*)((const char*)plw + rrow * 144 + (g << 4) + 64);
    __builtin_amdgcn_s_setprio(1);
#pragma unroll
    for (int nf = 0; nf < 4; ++nf) {
      bf16x8 v0 = *(const bf16x8*)(vlp + (nf * 16 + rrow) * 128 + ((g + 0) ^ rcb) * 16);
      bf16x8 v1 = *(const bf16x8*)(vlp + (nf * 16 + rrow) * 128 + ((g + 4) ^ rcb) * 16);
      oacc[nf] = __builtin_amdgcn_mfma_f32_16x16x32_bf16(pf0, v0, oacc[nf], 0, 0, 0);
      oacc[nf] = __builtin_amdgcn_mfma_f32_16x16x32_bf16(pf1, v1, oacc[nf], 0, 0, 0);
    }
    __builtin_amdgcn_s_setprio(0);
    __syncthreads();
  }
#undef ASTAGE

  float lsum = lacc[0] + lacc[1] + lacc[2] + lacc[3];
  lsum += __shfl_xor(lsum, 16);
  lsum += __shfl_xor(lsum, 32);
  const float inv = 1.0f / lsum;
  float invq[4];
#pragma unroll
  for (int r = 0; r < 4; ++r) {
    int bi = __builtin_amdgcn_ds_bpermute(((g << 2) + r) << 2,
                                          __builtin_bit_cast(int, inv));
    invq[r] = __builtin_bit_cast(float, bi);
  }
  u16* ob = aout + (size_t)((b << 10) + q0 + (wid << 4)) * 1024 + (h << 6);
#pragma unroll
  for (int nf = 0; nf < 4; ++nf)
#pragma unroll
    for (int r = 0; r < 4; ++r)
      ob[(size_t)(g * 4 + r) * 1024 + nf * 16 + rrow] = f2bf(oacc[nf][r] * invq[r]);
}

// ---------------- launcher ---------------------------------------------------------
extern "C" void kernel_launch(void* const* d_in, const int* in_sizes, int n_in,
                              void* d_out, int out_size, void* d_ws, size_t ws_size,
                              hipStream_t stream) {
  const float* x = (const float*)d_in[0];
  const float* ln1_g = (const float*)d_in[1];
  const float* ln1_b = (const float*)d_in[2];
  const float* w_qkv = (const float*)d_in[3];
  const float* b_qkv = (const float*)d_in[4];
  const float* w_o = (const float*)d_in[5];
  const float* b_o = (const float*)d_in[6];
  const float* ln2_g = (const float*)d_in[7];
  const float* ln2_b = (const float*)d_in[8];
  const float* w_fc1 = (const float*)d_in[9];
  const float* b_fc1 = (const float*)d_in[10];
  const float* w_fc2 = (const float*)d_in[11];
  const float* b_fc2 = (const float*)d_in[12];
  float* out = (float*)d_out;

  char* w = (char*)d_ws;
  u16* wqkvT = (u16*)w; w += (size_t)3072 * 1024 * 2;
  u16* woT   = (u16*)w; w += (size_t)1024 * 1024 * 2;
  u16* wfc1T = (u16*)w; w += (size_t)4096 * 1024 * 2;
  u16* wfc2T = (u16*)w; w += (size_t)1024 * 4096 * 2;
  u16* xn    = (u16*)w; w += (size_t)8192 * 1024 * 2;
  u16* qkvb  = (u16*)w; w += (size_t)8192 * 3072 * 2;
  u16* vtb   = (u16*)w; w += (size_t)128 * 64 * 1024 * 2;
  u16* attnb = (u16*)w; w += (size_t)8192 * 1024 * 2;
  u16* hbuf  = qkvb;  // overlay: qkv+vt dead when h is produced

  const float QS = 0.18033688011112042f;  // 0.125 * log2(e)

  wtrans4<<<3072, 256, 0, stream>>>(w_qkv, w_o, w_fc1, w_fc2, wqkvT, woT, wfc1T, wfc2T);

  lnorm<<<2048, 256, 0, stream>>>(x, ln1_g, ln1_b, xn);
  g97<0><<<1536, 256, 0, stream>>>(xn, wqkvT, b_qkv, nullptr, qkvb, 3072, 1024, QS, 1024, 24);
  vtrans<<<dim3(16, 128), 256, 0, stream>>>(qkvb, vtb);
  attn64<<<dim3(16, 128), 256, 0, stream>>>(qkvb, vtb, attnb);
  g97<2><<<512, 256, 0, stream>>>(attnb, woT, b_o, x, out, 1024, 1024, 1.f, 0, 8);
  lnorm<<<2048, 256, 0, stream>>>(out, ln2_g, ln2_b, xn);
  g97<1><<<2048, 256, 0, stream>>>(xn, wfc1T, b_fc1, nullptr, hbuf, 4096, 1024, 1.f, 0, 32);
  g97<2><<<512, 256, 0, stream>>>(hbuf, wfc2T, b_fc2, out, out, 1024, 4096, 1.f, 0, 8);
}